// Round 17
// baseline (151.386 us; speedup 1.0000x reference)
//
#include <hip/hip_runtime.h>
#include <math.h>

#define BATCH 2048
#define NN 64
#define FEAT 40
#define M 10
#define NPAIR 32      // 64 rows stored as 32 float2 row-pairs (interleaved)
#define PPAD 34       // one-ahead prefetch reads reach pair 32; pad

__device__ __forceinline__ float rl(float v, int l) {   // readlane (uniform l)
    return __int_as_float(__builtin_amdgcn_readlane(__float_as_int(v), l));
}
__device__ __forceinline__ int rli(int v, int l) {
    return __builtin_amdgcn_readlane(v, l);
}
__device__ __forceinline__ float wsum(float v) {
#pragma unroll
    for (int o = 32; o >= 1; o >>= 1) v += __shfl_xor(v, o, 64);
    return v;
}

// R17: TWO waves per batch element (block=128). R16's 77us was TLP-starved:
// grid-fixed 2 waves/SIMD, VALUBusy 51%, serial pivot chains half-hidden.
// Split: pivot chain + peel/capture registers kept REDUNDANTLY in both waves
// (cheap, keeps the spine barrier-free); Gram rows 32/32; wave1 owns the
// 11-chain z-solve + epilogue; Schur stream pairs split asymmetrically
// (W1 = rem/2 - 2) to balance. One 2-wave barrier per rank-2 step (31/pass)
// protects the cross-step capture-pair dependence; within-step read/write
// sets are disjoint per wave. Unlike R7/R8 (4-wave, LDS-serialized spine,
// 64 barriers) the spine here never leaves registers.
__global__ __launch_bounds__(128)
__attribute__((amdgpu_waves_per_eu(4, 4)))
void muygps_kernel(
    const float* __restrict__ x,      // (20000, 40)
    const float* __restrict__ ls,     // (10,)
    const float* __restrict__ epsv,   // (10,)
    const int*   __restrict__ bidx,   // (2048,)
    const int*   __restrict__ nidx,   // (2048, 64)
    const float* __restrict__ tgt,    // (2048, 64, 10)
    float* __restrict__ out,          // pred | var | sigma
    float* __restrict__ ws)           // (M, BATCH) sigma contributions
{
    __shared__ float2 Ap[PPAD * NN];  // pair p, lane: {A[2p][lane], A[2p+1][lane]}

    const int b    = blockIdx.x;
    const int w    = threadIdx.x >> 6;       // wave 0 or 1
    const int lane = threadIdx.x & 63;

    // ---- lane's neighbor row -> 40 statically-indexed VGPRs (both waves) ----
    const int nv = nidx[b * NN + lane];
    const float* xr0 = x + (size_t)nv * FEAT;
    float xc[FEAT];
#pragma unroll
    for (int q = 0; q < FEAT / 4; ++q) {
        const float4 v = *(const float4*)(xr0 + 4 * q);
        xc[4*q] = v.x; xc[4*q+1] = v.y; xc[4*q+2] = v.z; xc[4*q+3] = v.w;
    }
    float nl = 0.f;
#pragma unroll
    for (int f = 0; f < FEAT; ++f) nl = fmaf(xc[f], xc[f], nl);

    // ---- crosswise distance (wave 1 only: it owns z/epilogue) ----
    float cdv = 0.f;
    if (w == 1) {
        const float* xbp = x + (size_t)bidx[b] * FEAT;
        float gc = 0.f, nb = 0.f;
#pragma unroll
        for (int f = 0; f < FEAT; ++f) {
            const float bf = xbp[f];
            gc = fmaf(bf, xc[f], gc);     // identical chains -> exact cancel on dup
            nb = fmaf(bf, bf, nb);
        }
        float cd2 = (nb + nl) - 2.f * gc;
        cd2 = (cd2 < 0.05f) ? 0.f : cd2;  // legit d2 ~ 80 in 40-D N(0,1) data
        cdv = sqrtf(cd2);
    }

    unsigned done = 0;
    const unsigned all = (1u << M) - 1u;
    while (true) {
        const int   lead = __ffs(~done) - 1;     // block-uniform
        const float lls  = ls[lead];
        const float lep  = epsv[lead];
        const float il   = -1.0f / lls;

        // ---- Gram + kernel transform: wave w owns rows [32w, 32w+32) ----
        {
            const int r0b = w << 5;
#pragma unroll 2
            for (int it = 0; it < 32; it += 2) {
                const int i = r0b + it;
                const int ri0 = rli(nv, i), ri1 = rli(nv, i + 1);
                const float* r0 = x + (size_t)ri0 * FEAT;   // uniform -> s_loads
                const float* r1 = x + (size_t)ri1 * FEAT;
                float g0 = 0.f, g1 = 0.f;
#pragma unroll
                for (int f = 0; f < FEAT; ++f) {
                    g0 = fmaf(r0[f], xc[f], g0);
                    g1 = fmaf(r1[f], xc[f], g1);
                }
                float d2a = (rl(g0, i) + nl) - 2.f * g0;    // Gram diag = |x_i|^2
                float d2b = (rl(g1, i + 1) + nl) - 2.f * g1;
                d2a = (d2a < 0.05f) ? 0.f : d2a;
                d2b = (d2b < 0.05f) ? 0.f : d2b;
                float va = __expf(sqrtf(d2a) * il);
                float vb = __expf(sqrtf(d2b) * il);
                if (lane == i)     va += lep;
                if (lane == i + 1) vb += lep;
                Ap[(i >> 1) * NN + lane] = float2{va, vb};  // ds_write_b64
            }
        }

        // ---- RHS registers (wave 1): z[0]=Kc, z[1..10]=targets ----
        float z[M + 1];
        if (w == 1) {
            z[0] = __expf(cdv * il);
            const float* trow = tgt + ((size_t)b * NN + lane) * M;
#pragma unroll
            for (int q = 0; q < M / 2; ++q) {
                const float2 v = *(const float2*)(trow + 2 * q);
                z[2 * q + 1] = v.x; z[2 * q + 2] = v.y;
            }
        } else {
#pragma unroll
            for (int j = 0; j < M + 1; ++j) z[j] = 0.f;
        }
        __syncthreads();

        // ---- fused rank-2 LDL^T + solves; pivot spine redundant per wave ----
        float2 pv = Ap[lane];             // pair 0 -> pivot rows 0,1
        float pc0 = pv.x, pc1 = pv.y;
        float2 nn2 = Ap[NN + lane];       // pair 1 -> next pivots
        float n2 = nn2.x, n3 = nn2.y;
        float rvv = 0.f;                  // this lane's 1/D[lane]
        for (int p = 0; p < 31; ++p) {
            const int k = 2 * p;
            const int qs = p + 3;                        // stream start pair
            const float2 V = Ap[(p + 2) * NN + lane];    // capture pair
            // pivot chain (register-only, both waves)
            const float d0  = rl(pc0, k);
            const float r0  = __builtin_amdgcn_rcpf(d0);
            const float cv0 = pc0 * (-r0);
            pc1 = fmaf(cv0, rl(pc0, k + 1), pc1);
            const float d1  = rl(pc1, k + 1);
            const float r1  = __builtin_amdgcn_rcpf(d1);
            const float cv1 = pc1 * (-r1);
            rvv = (lane == k)     ? r0 : rvv;
            rvv = (lane == k + 1) ? r1 : rvv;
            // fused solve updates (wave 1 only)
            if (w == 1) {
                const float lv0 = (lane > k)     ? cv0 : 0.f;
                const float lv1 = (lane > k + 1) ? cv1 : 0.f;
#pragma unroll
                for (int j = 0; j < M + 1; ++j) {
                    z[j] = fmaf(lv0, rl(z[j], k), z[j]);
                    z[j] = fmaf(lv1, rl(z[j], k + 1), z[j]);
                }
            }
            // peel pair p+1 -> next pivots; capture pair p+2 (both waves)
            const float t2 = fmaf(cv1, rl(pc1, k + 2), fmaf(cv0, rl(pc0, k + 2), n2));
            const float t3 = fmaf(cv1, rl(pc1, k + 3), fmaf(cv0, rl(pc0, k + 3), n3));
            n2 = fmaf(cv1, rl(pc1, k + 4), fmaf(cv0, rl(pc0, k + 4), V.x));
            n3 = fmaf(cv1, rl(pc1, k + 5), fmaf(cv0, rl(pc0, k + 5), V.y));
            // stream pairs split: wave1 takes W1 tail pairs (balances z work)
            const int rem = NPAIR - qs;                  // 29-p
            int W1 = rem / 2 - 2; if (W1 < 0) W1 = 0;
            const int lo = (w == 0) ? qs : NPAIR - W1;
            const int hi = (w == 0) ? NPAIR - W1 : NPAIR;
            if (lo < hi) {
                float2 U = Ap[lo * NN + lane];           // one-ahead prefetch
                for (int q = lo; q < hi; ++q) {
                    float2 cur = U;
                    U = Ap[(q + 1) * NN + lane];         // pad-safe at q=31
                    const int i0 = 2 * q;
                    cur.x = fmaf(cv0, rl(pc0, i0),     fmaf(cv1, rl(pc1, i0),     cur.x));
                    cur.y = fmaf(cv0, rl(pc0, i0 + 1), fmaf(cv1, rl(pc1, i0 + 1), cur.y));
                    Ap[q * NN + lane] = cur;             // ds_write_b64
                }
            }
            pc0 = t2; pc1 = t3;
            __syncthreads();                             // writes -> next-step reads
        }
        {   // final step k=62 (rows 62,63 in pc0,pc1; both waves)
            const float d0  = rl(pc0, 62);
            const float r0  = __builtin_amdgcn_rcpf(d0);
            const float cv0 = pc0 * (-r0);
            pc1 = fmaf(cv0, rl(pc0, 63), pc1);
            const float d1  = rl(pc1, 63);
            const float r1  = __builtin_amdgcn_rcpf(d1);
            rvv = (lane == 62) ? r0 : rvv;
            rvv = (lane == 63) ? r1 : rvv;
            if (w == 1) {
                const float lv0 = (lane > 62) ? cv0 : 0.f;   // col 63 affects nobody
#pragma unroll
                for (int j = 0; j < M + 1; ++j)
                    z[j] = fmaf(lv0, rl(z[j], 62), z[j]);
            }
        }

        // ---- epilogue (wave 1): quadratic forms, lane-parallel stores ----
        unsigned mb = 0;
#pragma unroll
        for (int m = 0; m < M; ++m)
            if (!(done & (1u << m)) && ls[m] == lls && epsv[m] == lep)
                mb |= 1u << m;
        if (w == 1) {
            const float zc  = z[0];
            const float quad = wsum(zc * zc * rvv);
            float predv = 0.f, sigv = 0.f;
#pragma unroll
            for (int m = 0; m < M; ++m) {
                if (mb & (1u << m)) {
                    const float zm = z[m + 1];
                    const float pm = wsum(zc * zm * rvv);
                    const float sm = wsum(zm * zm * rvv);
                    if (lane == m) { predv = pm; sigv = sm; }
                }
            }
            if (lane < M && ((mb >> lane) & 1u)) {
                out[b * M + lane] = predv;
                out[BATCH * M + b * M + lane] = 1.0f - quad;
                ws[lane * BATCH + b] = sigv;
            }
        }
        done |= mb;
        if (done == all) break;
        __syncthreads();   // protect Ap reuse across group iterations
    }
}

// 1 block x 640: wave w reduces model w's 2048 contributions.
__global__ __launch_bounds__(640)
void sigma_reduce(const float* __restrict__ ws, float* __restrict__ out) {
    const int w = threadIdx.x >> 6, lane = threadIdx.x & 63;
    const float4* p = (const float4*)(ws + w * BATCH);
    float a = 0.f;
#pragma unroll
    for (int i = 0; i < BATCH / 4 / 64; ++i) {
        const float4 v = p[i * 64 + lane];
        a += (v.x + v.y) + (v.z + v.w);
    }
    a = wsum(a);
    if (lane == 0)
        out[2 * BATCH * M + w] = a * (1.0f / (float)(BATCH * NN));
}

extern "C" void kernel_launch(void* const* d_in, const int* in_sizes, int n_in,
                              void* d_out, int out_size, void* d_ws, size_t ws_size,
                              hipStream_t stream) {
    const float* x   = (const float*)d_in[0];
    const float* lsp = (const float*)d_in[1];
    const float* ep  = (const float*)d_in[2];
    const int*   bi  = (const int*)d_in[3];
    const int*   ni  = (const int*)d_in[4];
    const float* tg  = (const float*)d_in[5];
    float* out = (float*)d_out;
    float* ws  = (float*)d_ws;        // M*BATCH*4 = 80 KB

    muygps_kernel<<<BATCH, 128, 0, stream>>>(x, lsp, ep, bi, ni, tg, out, ws);
    sigma_reduce<<<1, 640, 0, stream>>>(ws, out);
}